// Round 17
// baseline (159.665 us; speedup 1.0000x reference)
//
#include <hip/hip_runtime.h>

// GRAPHEDX forward — fp32 v17: v14 (151.8us best) with ONE change:
// k_sink_t + k_sinkhorn fused into per-graph k_tail (tq/tc in LDS,
// one fewer dispatch). Everything else byte-identical to v14.

constexpr int kB    = 48;
constexpr int kNM   = 20;
constexpr int kD    = 32;
constexpr int kNP   = 190;
constexpr int kNTOT = 1728;
constexpr int kIters = 20;
constexpr float kInvT = 100.0f;

__device__ __forceinline__ void pair_sd(int p, int& s, int& d) {
    int row = 0, rem = p;
    #pragma unroll
    for (int r = 0; r < 19; ++r) {
        int len = 19 - r;
        if (rem < len) { row = r; break; }
        rem -= len;
    }
    s = row; d = row + 1 + rem;
}

__device__ __forceinline__ float bc(float v, int k) {
    return __int_as_float(__builtin_amdgcn_readlane(__float_as_int(v), k));
}

__device__ __forceinline__ void lse20(float (&r)[20]) {
    float m01 = fmaxf(r[0], r[1]),  m23 = fmaxf(r[2], r[3]),
          m45 = fmaxf(r[4], r[5]),  m67 = fmaxf(r[6], r[7]),
          m89 = fmaxf(r[8], r[9]),  mab = fmaxf(r[10], r[11]),
          mcd = fmaxf(r[12], r[13]), mef = fmaxf(r[14], r[15]),
          mgh = fmaxf(r[16], r[17]), mij = fmaxf(r[18], r[19]);
    float n0 = fmaxf(m01, m23), n1 = fmaxf(m45, m67), n2 = fmaxf(m89, mab),
          n3 = fmaxf(mcd, mef), n4 = fmaxf(mgh, mij);
    float m = fmaxf(fmaxf(fmaxf(n0, n1), fmaxf(n2, n3)), n4);
    float e[20];
    #pragma unroll
    for (int k = 0; k < 20; ++k) e[k] = __expf(r[k] - m);
    float s01 = e[0] + e[1],  s23 = e[2] + e[3],  s45 = e[4] + e[5],
          s67 = e[6] + e[7],  s89 = e[8] + e[9],  sab = e[10] + e[11],
          scd = e[12] + e[13], sef = e[14] + e[15], sgh = e[16] + e[17],
          sij = e[18] + e[19];
    float t0 = s01 + s23, t1 = s45 + s67, t2 = s89 + sab,
          t3 = scd + sef, t4 = sgh + sij;
    float s = ((t0 + t1) + (t2 + t3)) + t4;
    float l = m + __logf(s);
    #pragma unroll
    for (int k = 0; k < 20; ++k) r[k] -= l;
}

// ---------------- fused encoders + zeroing ----------------
__global__ void k_enc(const float* __restrict__ nf, const float* __restrict__ nw,
                      const float* __restrict__ nb, const float* __restrict__ ef,
                      const float* __restrict__ ew, const float* __restrict__ eb,
                      float* __restrict__ h, float* __restrict__ ee,
                      float* __restrict__ agg, float* __restrict__ out) {
    int tid = blockIdx.x * 256 + threadIdx.x;
    int stride = gridDim.x * 256;
    for (int i = tid; i < kNTOT * 32; i += stride) {
        int n = i >> 5, c = i & 31;
        float acc = nb[c];
        const float* row = nf + n * 16;
        #pragma unroll
        for (int k = 0; k < 16; ++k) acc = fmaf(row[k], nw[k * 32 + c], acc);
        h[i] = acc;
    }
    for (int i = tid; i < 6720 * 16; i += stride) {
        int n = i >> 4, c = i & 15;
        float acc = eb[c];
        const float* row = ef + n * 8;
        #pragma unroll
        for (int k = 0; k < 8; ++k) acc = fmaf(row[k], ew[k * 16 + c], acc);
        ee[i] = acc;
    }
    for (int i = tid; i < kNTOT * 64; i += stride) agg[i] = 0.f;
    if (tid < kB) out[tid] = 0.f;
}

// ---------------- message + scatter: readlane MLP, 2 edges/wave (v12) ----------
__global__ void __launch_bounds__(256)
k_msg(const float* __restrict__ h, const float* __restrict__ ee,
      const int* __restrict__ fidx, const int* __restrict__ tidx,
      const float* __restrict__ w1, const float* __restrict__ b1,
      const float* __restrict__ w2, const float* __restrict__ b2,
      float* __restrict__ agg) {
    int w = threadIdx.x >> 6, lane = threadIdx.x & 63;
    int e0 = (blockIdx.x * 4 + w) * 2;                 // 840 blocks, 6720 edges
    int toj[2]; float xa[2], xb[2], acc[2], o[2];
    #pragma unroll
    for (int j = 0; j < 2; ++j) {
        int e = e0 + j;
        int fr = fidx[e]; toj[j] = tidx[e];
        xa[j] = h[(lane < 32 ? fr : toj[j]) * kD + (lane & 31)];
        xb[j] = ee[e * 16 + (lane & 15)];
        acc[j] = b1[lane];
    }
    #pragma unroll
    for (int k = 0; k < 64; ++k) {
        float w1k = w1[k * 64 + lane];
        #pragma unroll
        for (int j = 0; j < 2; ++j) acc[j] = fmaf(bc(xa[j], k), w1k, acc[j]);
    }
    #pragma unroll
    for (int k = 0; k < 16; ++k) {
        float w1k = w1[(64 + k) * 64 + lane];
        #pragma unroll
        for (int j = 0; j < 2; ++j) acc[j] = fmaf(bc(xb[j], k), w1k, acc[j]);
    }
    #pragma unroll
    for (int j = 0; j < 2; ++j) { acc[j] = fmaxf(acc[j], 0.f); o[j] = b2[lane]; }
    #pragma unroll
    for (int k = 0; k < 64; ++k) {
        float w2k = w2[k * 64 + lane];
        #pragma unroll
        for (int j = 0; j < 2; ++j) o[j] = fmaf(bc(acc[j], k), w2k, o[j]);
    }
    #pragma unroll
    for (int j = 0; j < 2; ++j) atomicAdd(&agg[toj[j] * 64 + lane], o[j]);
}

// ---------------- node update: readlane MLP, 2 nodes/wave (v12) ----------------
__global__ void __launch_bounds__(256)
k_upd(float* __restrict__ h, float* __restrict__ agg,
      const float* __restrict__ w1, const float* __restrict__ b1,
      const float* __restrict__ w2, const float* __restrict__ b2) {
    int w = threadIdx.x >> 6, lane = threadIdx.x & 63;
    int n0 = (blockIdx.x * 4 + w) * 2;                 // 216 blocks, 1728 nodes
    float xa[2], xb[2], acc[2], o[2];
    #pragma unroll
    for (int j = 0; j < 2; ++j) {
        int n = n0 + j;
        xa[j] = agg[n * 64 + lane];
        agg[n * 64 + lane] = 0.f;                      // re-zero for next round
        xb[j] = h[n * kD + (lane & 31)];
        acc[j] = b1[lane];
    }
    #pragma unroll
    for (int k = 0; k < 64; ++k) {
        float w1k = w1[k * 64 + lane];
        #pragma unroll
        for (int j = 0; j < 2; ++j) acc[j] = fmaf(bc(xa[j], k), w1k, acc[j]);
    }
    #pragma unroll
    for (int k = 0; k < 32; ++k) {
        float w1k = w1[(64 + k) * 64 + lane];
        #pragma unroll
        for (int j = 0; j < 2; ++j) acc[j] = fmaf(bc(xb[j], k), w1k, acc[j]);
    }
    #pragma unroll
    for (int j = 0; j < 2; ++j) { acc[j] = fmaxf(acc[j], 0.f); o[j] = b2[lane & 31]; }
    #pragma unroll
    for (int k = 0; k < 64; ++k) {
        float w2k = w2[k * 32 + (lane & 31)];
        #pragma unroll
        for (int j = 0; j < 2; ++j) o[j] = fmaf(bc(acc[j], k), w2k, o[j]);
    }
    if (lane < 32) {
        #pragma unroll
        for (int j = 0; j < 2; ++j) h[(n0 + j) * kD + lane] += o[j];
    }
}

// ---------------- k_tail: per-graph sink_t + sinkhorn + node_align ----------------
__global__ void __launch_bounds__(256)
k_tail(const float* __restrict__ h,
       const float* __restrict__ w1, const float* __restrict__ b1,
       const float* __restrict__ w2, const float* __restrict__ b2,
       float* __restrict__ Hq, float* __restrict__ Hc,
       float* __restrict__ P, float* __restrict__ out) {
    __shared__ float tqS[400], tcS[400];
    __shared__ float trS[20 * 21];
    int b = blockIdx.x;                                // 48 blocks
    int t = threadIdx.x, lane = t & 63, wave = t >> 6;

    // sink MLP: 40 tasks over 4 waves (readlane pattern, wave-autonomous)
    for (int task = wave; task < 40; task += 4) {
        int side = task >= 20, i = task - side * 20;
        float v = 0.f;
        if (lane < 32) {
            if (!side)        v = h[(b * 36 + i) * kD + lane];
            else if (i < 16)  v = h[(b * 36 + 20 + i) * kD + lane];
            (side ? Hc : Hq)[(b * kNM + i) * kD + lane] = v;
        }
        int tt = lane < 20 ? lane : 0;
        float acc = b1[tt];
        #pragma unroll
        for (int k = 0; k < 32; ++k) acc = fmaf(bc(v, k), w1[k * 20 + tt], acc);
        acc = fmaxf(acc, 0.f);
        float o = b2[tt];
        #pragma unroll
        for (int k = 0; k < 20; ++k) o = fmaf(bc(acc, k), w2[k * 20 + tt], o);
        if (lane < 20) (side ? tcS : tqS)[i * 20 + lane] = o;
    }
    __syncthreads();

    // sinkhorn (register rows) — all threads hit barriers, t<20 do work
    float r[20];
    if (t < 20) {
        float tqr[20];
        #pragma unroll
        for (int k = 0; k < 20; ++k) tqr[k] = tqS[t * 20 + k];
        #pragma unroll
        for (int j = 0; j < 20; ++j) {
            float c = 0.f;
            #pragma unroll
            for (int k = 0; k < 20; ++k) c += fabsf(tqr[k] - tcS[j * 20 + k]);
            r[j] = -c * kInvT;
        }
    }
    for (int it = 0; it < kIters; ++it) {
        if (t < 20) {
            lse20(r);
            #pragma unroll
            for (int j = 0; j < 20; ++j) trS[t * 21 + j] = r[j];
        }
        __syncthreads();
        if (t < 20) {
            #pragma unroll
            for (int i = 0; i < 20; ++i) r[i] = trS[i * 21 + t];
            lse20(r);
            #pragma unroll
            for (int i = 0; i < 20; ++i) trS[i * 21 + t] = r[i];
        }
        __syncthreads();
        if (t < 20) {
            #pragma unroll
            for (int j = 0; j < 20; ++j) r[j] = trS[t * 21 + j];
        }
        __syncthreads();
    }
    float part = 0.f;
    if (t < 20) {
        float pv[20];
        #pragma unroll
        for (int j = 0; j < 20; ++j) pv[j] = __expf(r[j]);
        float* Pb = P + b * 400 + t * 20;
        #pragma unroll
        for (int j = 0; j < 20; ++j) Pb[j] = pv[j];
        float pr4 = (pv[16] + pv[17]) + (pv[18] + pv[19]);
        float l1 = 0.f;
        const float* hq = h + (b * 36 + t) * kD;       // Hq row i<20 == h row i
        #pragma unroll
        for (int k = 0; k < 32; ++k) l1 += fabsf(hq[k]);
        part = pr4 * l1;
    }
    if (t < 64) {
        #pragma unroll
        for (int off = 32; off; off >>= 1) part += __shfl_down(part, off, 64);
        if (t == 0) atomicAdd(&out[b], part);
    }
}

// ---------------- edge embeddings: XCD-affine, 4 tasks/wave ----------------
__global__ void __launch_bounds__(256)
k_edge_emb(const float* __restrict__ Hq, const float* __restrict__ Hc,
           const float* __restrict__ qadj, const float* __restrict__ cadj,
           const float* __restrict__ w1, const float* __restrict__ b1,
           const float* __restrict__ w2, const float* __restrict__ b2,
           float* __restrict__ Eq, float* __restrict__ Ec) {
    int w = threadIdx.x >> 6, lane = threadIdx.x & 63;
    int xcd = blockIdx.x & 7, slot = blockIdx.x >> 3;  // grid 1152
    int b = xcd + 8 * (slot / 24);
    int r = slot % 24;
    float xa[4], ev[4], af[4], ab[4];
    int sidej[4], pj[4];
    #pragma unroll
    for (int j = 0; j < 4; ++j) {
        int tloc = r * 16 + w * 4 + j;
        if (tloc >= 380) tloc = 379;
        sidej[j] = tloc / kNP; pj[j] = tloc % kNP;
        int s, d; pair_sd(pj[j], s, d);
        const float* H = sidej[j] ? Hc : Hq;
        xa[j] = (lane < 32) ? H[(b * kNM + s) * kD + lane]
                            : H[(b * kNM + d) * kD + (lane - 32)];
        ev[j] = (sidej[j] ? cadj : qadj)[b * 400 + s * 20 + d];
        float bb = b1[lane];
        af[j] = bb; ab[j] = bb;
    }
    #pragma unroll
    for (int k = 0; k < 64; ++k) {
        float w1k = w1[k * 64 + lane];
        #pragma unroll
        for (int j = 0; j < 4; ++j) {
            af[j] = fmaf(bc(xa[j], k),      w1k, af[j]);
            ab[j] = fmaf(bc(xa[j], k ^ 32), w1k, ab[j]);
        }
    }
    {
        float w1e = w1[64 * 64 + lane];
        #pragma unroll
        for (int j = 0; j < 4; ++j) {
            af[j] = fmaf(ev[j], w1e, af[j]);
            ab[j] = fmaf(ev[j], w1e, ab[j]);
        }
    }
    float hid[4], o[4];
    #pragma unroll
    for (int j = 0; j < 4; ++j) {
        hid[j] = fmaxf(af[j], 0.f) + fmaxf(ab[j], 0.f);
        o[j] = 2.f * b2[lane];
    }
    #pragma unroll
    for (int k = 0; k < 64; ++k) {
        float w2k = w2[k * 64 + lane];
        #pragma unroll
        for (int j = 0; j < 4; ++j) o[j] = fmaf(bc(hid[j], k), w2k, o[j]);
    }
    #pragma unroll
    for (int j = 0; j < 4; ++j)
        (sidej[j] ? Ec : Eq)[(b * kNP + pj[j]) * 64 + lane] = o[j];
}

// ---------------- edge_align: named-scalar ec tile + prefetch (v14) ----------
#define EC_ALL(X) X(0) X(1) X(2) X(3) X(4) X(5) X(6) X(7) X(8) X(9) X(10) X(11) \
  X(12) X(13) X(14) X(15) X(16) X(17) X(18) X(19) X(20) X(21) X(22) X(23) \
  X(24) X(25) X(26) X(27) X(28) X(29) X(30) X(31)

__global__ void __launch_bounds__(256, 4)
k_final(const float* __restrict__ P, const float* __restrict__ Eq,
        const float* __restrict__ Ec, const float* __restrict__ qadj,
        const float* __restrict__ cadj, float* __restrict__ out) {
    __shared__ float Ps[400];
    __shared__ unsigned char spsh[192], dpsh[192];
    int xcd = blockIdx.x & 7, slot = blockIdx.x >> 3;  // grid 288
    int b = xcd + 8 * (slot / 6), qt = slot % 6;
    int t = threadIdx.x, w = t >> 6, lane = t & 63;
    if (t < 192) {
        int s = 0, d = 0;
        if (t < kNP) pair_sd(t, s, d);
        spsh[t] = (unsigned char)s;
        dpsh[t] = (unsigned char)d;
    }
    for (int i = t; i < 400; i += 256) Ps[i] = P[b * 400 + i];
    __syncthreads();

    int l31 = lane & 31;
    int q = qt * 32 + l31;
    bool qv = q < kNP;
    int sq = spsh[qv ? q : 0], dq = dpsh[qv ? q : 0];
    float acv = qv ? cadj[b * 400 + sq * 20 + dq] : 0.f;

    const float* ecb = Ec + (b * kNP + qt * 32) * 64 + lane;
#define EC_DECL(i) float ec##i = (qt * 32 + i < kNP) ? ecb[i * 64] : 0.f;
    EC_ALL(EC_DECL)
#undef EC_DECL

    float a0 = 0.f, a1 = 0.f, a2 = 0.f, a3 = 0.f;
    int pp = w;
    float aqc = qadj[b * 400 + spsh[pp] * 20 + dpsh[pp]];
    float eqc = Eq[(b * kNP + pp) * 64 + lane];
    while (pp < kNP) {
        int pn = pp + 4;
        float aqn = 0.f, eqn = 0.f;
        if (pn < kNP) {
            aqn = qadj[b * 400 + spsh[pn] * 20 + dpsh[pn]];
            eqn = Eq[(b * kNP + pn) * 64 + lane];
        }
        int sp = spsh[pp], dp = dpsh[pp];
        float eT = Ps[sp * 20 + sq] * Ps[dp * 20 + dq]
                 + Ps[sp * 20 + dq] * Ps[dp * 20 + sq];
        float wqv = qv ? ((aqc > 0.5f) ? (1.f - acv) : acv) * eT : 0.f;
#define EC_FMA(i) { float d_ = fabsf(eqc - ec##i); \
        if ((i & 3) == 0) a0 = fmaf(bc(wqv, i), d_, a0); \
        else if ((i & 3) == 1) a1 = fmaf(bc(wqv, i), d_, a1); \
        else if ((i & 3) == 2) a2 = fmaf(bc(wqv, i), d_, a2); \
        else a3 = fmaf(bc(wqv, i), d_, a3); }
        EC_ALL(EC_FMA)
#undef EC_FMA
        aqc = aqn; eqc = eqn; pp = pn;
    }
    float partial = (a0 + a1) + (a2 + a3);
    #pragma unroll
    for (int off = 32; off; off >>= 1) partial += __shfl_down(partial, off, 64);
    if (lane == 0) atomicAdd(&out[b], partial);
}

extern "C" void kernel_launch(void* const* d_in, const int* in_sizes, int n_in,
                              void* d_out, int out_size, void* d_ws, size_t ws_size,
                              hipStream_t stream) {
    auto f = [&](int i) { return (const float*)d_in[i]; };
    const float* nf   = f(0);
    const float* ef   = f(1);
    const float* qadj = f(2);
    const float* cadj = f(3);
    const int* from_idx = (const int*)d_in[24];
    const int* to_idx   = (const int*)d_in[25];
    float* out = (float*)d_out;

    float* ws  = (float*)d_ws;
    float* h   = ws;                       // 55296
    float* ee  = h   + 55296;              // 107520
    float* agg = ee  + 107520;             // 110592
    float* Hq  = agg + 110592;             // 30720
    float* Hc  = Hq  + 30720;              // 30720
    float* P   = Hc  + 30720;              // 19200
    float* Eq  = P   + 19200;              // 583680
    float* Ec  = Eq  + 583680;             // 583680

    k_enc<<<432, 256, 0, stream>>>(nf, f(4), f(5), ef, f(6), f(7), h, ee, agg, out);
    for (int it = 0; it < 5; ++it) {
        k_msg<<<840, 256, 0, stream>>>(h, ee, from_idx, to_idx,
                                       f(8), f(9), f(10), f(11), agg);
        k_upd<<<216, 256, 0, stream>>>(h, agg, f(12), f(13), f(14), f(15));
    }
    k_tail<<<48, 256, 0, stream>>>(h, f(16), f(17), f(18), f(19), Hq, Hc, P, out);
    k_edge_emb<<<1152, 256, 0, stream>>>(Hq, Hc, qadj, cadj,
                                         f(20), f(21), f(22), f(23), Eq, Ec);
    k_final<<<288, 256, 0, stream>>>(P, Eq, Ec, qadj, cadj, out);
}

// Round 18
// 150.983 us; speedup vs baseline: 1.0575x; 1.0575x over previous
//
#include <hip/hip_runtime.h>

// GRAPHEDX forward — fp32 v18: v14 (151.8us best) reverted, with one zero-risk
// change: k_final issues ec/acv loads BEFORE Ps staging+barrier (T14 overlap).

constexpr int kB    = 48;
constexpr int kNM   = 20;
constexpr int kD    = 32;
constexpr int kNP   = 190;
constexpr int kNTOT = 1728;
constexpr int kIters = 20;
constexpr float kInvT = 100.0f;

__device__ __forceinline__ void pair_sd(int p, int& s, int& d) {
    int row = 0, rem = p;
    #pragma unroll
    for (int r = 0; r < 19; ++r) {
        int len = 19 - r;
        if (rem < len) { row = r; break; }
        rem -= len;
    }
    s = row; d = row + 1 + rem;
}

__device__ __forceinline__ float bc(float v, int k) {
    return __int_as_float(__builtin_amdgcn_readlane(__float_as_int(v), k));
}

__device__ __forceinline__ void lse20(float (&r)[20]) {
    float m01 = fmaxf(r[0], r[1]),  m23 = fmaxf(r[2], r[3]),
          m45 = fmaxf(r[4], r[5]),  m67 = fmaxf(r[6], r[7]),
          m89 = fmaxf(r[8], r[9]),  mab = fmaxf(r[10], r[11]),
          mcd = fmaxf(r[12], r[13]), mef = fmaxf(r[14], r[15]),
          mgh = fmaxf(r[16], r[17]), mij = fmaxf(r[18], r[19]);
    float n0 = fmaxf(m01, m23), n1 = fmaxf(m45, m67), n2 = fmaxf(m89, mab),
          n3 = fmaxf(mcd, mef), n4 = fmaxf(mgh, mij);
    float m = fmaxf(fmaxf(fmaxf(n0, n1), fmaxf(n2, n3)), n4);
    float e[20];
    #pragma unroll
    for (int k = 0; k < 20; ++k) e[k] = __expf(r[k] - m);
    float s01 = e[0] + e[1],  s23 = e[2] + e[3],  s45 = e[4] + e[5],
          s67 = e[6] + e[7],  s89 = e[8] + e[9],  sab = e[10] + e[11],
          scd = e[12] + e[13], sef = e[14] + e[15], sgh = e[16] + e[17],
          sij = e[18] + e[19];
    float t0 = s01 + s23, t1 = s45 + s67, t2 = s89 + sab,
          t3 = scd + sef, t4 = sgh + sij;
    float s = ((t0 + t1) + (t2 + t3)) + t4;
    float l = m + __logf(s);
    #pragma unroll
    for (int k = 0; k < 20; ++k) r[k] -= l;
}

// ---------------- fused encoders + zeroing ----------------
__global__ void k_enc(const float* __restrict__ nf, const float* __restrict__ nw,
                      const float* __restrict__ nb, const float* __restrict__ ef,
                      const float* __restrict__ ew, const float* __restrict__ eb,
                      float* __restrict__ h, float* __restrict__ ee,
                      float* __restrict__ agg, float* __restrict__ out) {
    int tid = blockIdx.x * 256 + threadIdx.x;
    int stride = gridDim.x * 256;
    for (int i = tid; i < kNTOT * 32; i += stride) {
        int n = i >> 5, c = i & 31;
        float acc = nb[c];
        const float* row = nf + n * 16;
        #pragma unroll
        for (int k = 0; k < 16; ++k) acc = fmaf(row[k], nw[k * 32 + c], acc);
        h[i] = acc;
    }
    for (int i = tid; i < 6720 * 16; i += stride) {
        int n = i >> 4, c = i & 15;
        float acc = eb[c];
        const float* row = ef + n * 8;
        #pragma unroll
        for (int k = 0; k < 8; ++k) acc = fmaf(row[k], ew[k * 16 + c], acc);
        ee[i] = acc;
    }
    for (int i = tid; i < kNTOT * 64; i += stride) agg[i] = 0.f;
    if (tid < kB) out[tid] = 0.f;
}

// ---------------- message + scatter: readlane MLP, 2 edges/wave ----------------
__global__ void __launch_bounds__(256)
k_msg(const float* __restrict__ h, const float* __restrict__ ee,
      const int* __restrict__ fidx, const int* __restrict__ tidx,
      const float* __restrict__ w1, const float* __restrict__ b1,
      const float* __restrict__ w2, const float* __restrict__ b2,
      float* __restrict__ agg) {
    int w = threadIdx.x >> 6, lane = threadIdx.x & 63;
    int e0 = (blockIdx.x * 4 + w) * 2;                 // 840 blocks, 6720 edges
    int toj[2]; float xa[2], xb[2], acc[2], o[2];
    #pragma unroll
    for (int j = 0; j < 2; ++j) {
        int e = e0 + j;
        int fr = fidx[e]; toj[j] = tidx[e];
        xa[j] = h[(lane < 32 ? fr : toj[j]) * kD + (lane & 31)];
        xb[j] = ee[e * 16 + (lane & 15)];
        acc[j] = b1[lane];
    }
    #pragma unroll
    for (int k = 0; k < 64; ++k) {
        float w1k = w1[k * 64 + lane];
        #pragma unroll
        for (int j = 0; j < 2; ++j) acc[j] = fmaf(bc(xa[j], k), w1k, acc[j]);
    }
    #pragma unroll
    for (int k = 0; k < 16; ++k) {
        float w1k = w1[(64 + k) * 64 + lane];
        #pragma unroll
        for (int j = 0; j < 2; ++j) acc[j] = fmaf(bc(xb[j], k), w1k, acc[j]);
    }
    #pragma unroll
    for (int j = 0; j < 2; ++j) { acc[j] = fmaxf(acc[j], 0.f); o[j] = b2[lane]; }
    #pragma unroll
    for (int k = 0; k < 64; ++k) {
        float w2k = w2[k * 64 + lane];
        #pragma unroll
        for (int j = 0; j < 2; ++j) o[j] = fmaf(bc(acc[j], k), w2k, o[j]);
    }
    #pragma unroll
    for (int j = 0; j < 2; ++j) atomicAdd(&agg[toj[j] * 64 + lane], o[j]);
}

// ---------------- node update: readlane MLP, 2 nodes/wave ----------------
__global__ void __launch_bounds__(256)
k_upd(float* __restrict__ h, float* __restrict__ agg,
      const float* __restrict__ w1, const float* __restrict__ b1,
      const float* __restrict__ w2, const float* __restrict__ b2) {
    int w = threadIdx.x >> 6, lane = threadIdx.x & 63;
    int n0 = (blockIdx.x * 4 + w) * 2;                 // 216 blocks, 1728 nodes
    float xa[2], xb[2], acc[2], o[2];
    #pragma unroll
    for (int j = 0; j < 2; ++j) {
        int n = n0 + j;
        xa[j] = agg[n * 64 + lane];
        agg[n * 64 + lane] = 0.f;                      // re-zero for next round
        xb[j] = h[n * kD + (lane & 31)];
        acc[j] = b1[lane];
    }
    #pragma unroll
    for (int k = 0; k < 64; ++k) {
        float w1k = w1[k * 64 + lane];
        #pragma unroll
        for (int j = 0; j < 2; ++j) acc[j] = fmaf(bc(xa[j], k), w1k, acc[j]);
    }
    #pragma unroll
    for (int k = 0; k < 32; ++k) {
        float w1k = w1[(64 + k) * 64 + lane];
        #pragma unroll
        for (int j = 0; j < 2; ++j) acc[j] = fmaf(bc(xb[j], k), w1k, acc[j]);
    }
    #pragma unroll
    for (int j = 0; j < 2; ++j) { acc[j] = fmaxf(acc[j], 0.f); o[j] = b2[lane & 31]; }
    #pragma unroll
    for (int k = 0; k < 64; ++k) {
        float w2k = w2[k * 32 + (lane & 31)];
        #pragma unroll
        for (int j = 0; j < 2; ++j) o[j] = fmaf(bc(acc[j], k), w2k, o[j]);
    }
    if (lane < 32) {
        #pragma unroll
        for (int j = 0; j < 2; ++j) h[(n0 + j) * kD + lane] += o[j];
    }
}

// ---------------- Hq/Hc + sink t-vectors: XCD-affine ----------------
__global__ void k_sink_t(const float* __restrict__ h,
                         const float* __restrict__ w1, const float* __restrict__ b1,
                         const float* __restrict__ w2, const float* __restrict__ b2,
                         float* __restrict__ Hq, float* __restrict__ Hc,
                         float* __restrict__ tq, float* __restrict__ tc) {
    __shared__ float xs[4][32];
    __shared__ float hs[4][20];
    int w = threadIdx.x >> 6, lane = threadIdx.x & 63;
    int xcd = blockIdx.x & 7, slot = blockIdx.x >> 3;  // grid 480
    int b = xcd + 8 * (slot / 10);
    int task = (slot % 10) * 4 + w;
    int side = task >= 20;
    int i = task - side * 20;
    if (lane < 32) {
        float v;
        if (side == 0) v = h[(b * 36 + i) * kD + lane];
        else           v = (i < 16) ? h[(b * 36 + 20 + i) * kD + lane] : 0.f;
        (side ? Hc : Hq)[(b * kNM + i) * kD + lane] = v;
        xs[w][lane] = v;
    }
    __syncthreads();
    if (lane < kNM) {
        float acc = b1[lane];
        #pragma unroll
        for (int k = 0; k < kD; ++k) acc += xs[w][k] * w1[k * kNM + lane];
        hs[w][lane] = fmaxf(acc, 0.f);
    }
    __syncthreads();
    if (lane < kNM) {
        float o = b2[lane];
        #pragma unroll
        for (int k = 0; k < kNM; ++k) o += hs[w][k] * w2[k * kNM + lane];
        (side ? tc : tq)[(b * kNM + i) * kNM + lane] = o;
    }
}

// ---------------- Sinkhorn (v6) ----------------
__global__ void k_sinkhorn(const float* __restrict__ tq, const float* __restrict__ tc,
                           const float* __restrict__ Hq,
                           float* __restrict__ P, float* __restrict__ out) {
    __shared__ float tcS[400];
    __shared__ float tr[20 * 21];
    int b = blockIdx.x, lane = threadIdx.x;
    for (int i = lane; i < 400; i += 64) tcS[i] = tc[b * 400 + i];
    int i20 = lane < 20 ? lane : 0;
    float tqr[20];
    #pragma unroll
    for (int k = 0; k < 20; ++k) tqr[k] = tq[(b * 20 + i20) * 20 + k];
    __syncthreads();
    float r[20];
    #pragma unroll
    for (int j = 0; j < 20; ++j) {
        float c = 0.f;
        #pragma unroll
        for (int k = 0; k < 20; ++k) c += fabsf(tqr[k] - tcS[j * 20 + k]);
        r[j] = -c * kInvT;
    }
    for (int it = 0; it < kIters; ++it) {
        lse20(r);
        if (lane < 20) {
            #pragma unroll
            for (int j = 0; j < 20; ++j) tr[lane * 21 + j] = r[j];
        }
        __syncthreads();
        if (lane < 20) {
            #pragma unroll
            for (int i = 0; i < 20; ++i) r[i] = tr[i * 21 + lane];
        }
        __syncthreads();
        lse20(r);
        if (lane < 20) {
            #pragma unroll
            for (int i = 0; i < 20; ++i) tr[i * 21 + lane] = r[i];
        }
        __syncthreads();
        if (lane < 20) {
            #pragma unroll
            for (int j = 0; j < 20; ++j) r[j] = tr[lane * 21 + j];
        }
        __syncthreads();
    }
    float part = 0.f;
    if (lane < 20) {
        float pv[20];
        #pragma unroll
        for (int j = 0; j < 20; ++j) pv[j] = __expf(r[j]);
        float* Pb = P + b * 400 + lane * 20;
        #pragma unroll
        for (int j = 0; j < 20; ++j) Pb[j] = pv[j];
        float pr4 = (pv[16] + pv[17]) + (pv[18] + pv[19]);
        float l1 = 0.f;
        const float* hq = Hq + (b * 20 + lane) * 32;
        #pragma unroll
        for (int k = 0; k < 32; ++k) l1 += fabsf(hq[k]);
        part = pr4 * l1;
    }
    #pragma unroll
    for (int off = 32; off; off >>= 1) part += __shfl_down(part, off, 64);
    if (lane == 0) atomicAdd(&out[b], part);
}

// ---------------- edge embeddings: XCD-affine, 4 tasks/wave ----------------
__global__ void __launch_bounds__(256)
k_edge_emb(const float* __restrict__ Hq, const float* __restrict__ Hc,
           const float* __restrict__ qadj, const float* __restrict__ cadj,
           const float* __restrict__ w1, const float* __restrict__ b1,
           const float* __restrict__ w2, const float* __restrict__ b2,
           float* __restrict__ Eq, float* __restrict__ Ec) {
    int w = threadIdx.x >> 6, lane = threadIdx.x & 63;
    int xcd = blockIdx.x & 7, slot = blockIdx.x >> 3;  // grid 1152
    int b = xcd + 8 * (slot / 24);
    int r = slot % 24;
    float xa[4], ev[4], af[4], ab[4];
    int sidej[4], pj[4];
    #pragma unroll
    for (int j = 0; j < 4; ++j) {
        int tloc = r * 16 + w * 4 + j;
        if (tloc >= 380) tloc = 379;
        sidej[j] = tloc / kNP; pj[j] = tloc % kNP;
        int s, d; pair_sd(pj[j], s, d);
        const float* H = sidej[j] ? Hc : Hq;
        xa[j] = (lane < 32) ? H[(b * kNM + s) * kD + lane]
                            : H[(b * kNM + d) * kD + (lane - 32)];
        ev[j] = (sidej[j] ? cadj : qadj)[b * 400 + s * 20 + d];
        float bb = b1[lane];
        af[j] = bb; ab[j] = bb;
    }
    #pragma unroll
    for (int k = 0; k < 64; ++k) {
        float w1k = w1[k * 64 + lane];
        #pragma unroll
        for (int j = 0; j < 4; ++j) {
            af[j] = fmaf(bc(xa[j], k),      w1k, af[j]);
            ab[j] = fmaf(bc(xa[j], k ^ 32), w1k, ab[j]);
        }
    }
    {
        float w1e = w1[64 * 64 + lane];
        #pragma unroll
        for (int j = 0; j < 4; ++j) {
            af[j] = fmaf(ev[j], w1e, af[j]);
            ab[j] = fmaf(ev[j], w1e, ab[j]);
        }
    }
    float hid[4], o[4];
    #pragma unroll
    for (int j = 0; j < 4; ++j) {
        hid[j] = fmaxf(af[j], 0.f) + fmaxf(ab[j], 0.f);
        o[j] = 2.f * b2[lane];
    }
    #pragma unroll
    for (int k = 0; k < 64; ++k) {
        float w2k = w2[k * 64 + lane];
        #pragma unroll
        for (int j = 0; j < 4; ++j) o[j] = fmaf(bc(hid[j], k), w2k, o[j]);
    }
    #pragma unroll
    for (int j = 0; j < 4; ++j)
        (sidej[j] ? Ec : Eq)[(b * kNP + pj[j]) * 64 + lane] = o[j];
}

// ---------------- edge_align: ec/acv loads issued BEFORE staging (T14) ----------
#define EC_ALL(X) X(0) X(1) X(2) X(3) X(4) X(5) X(6) X(7) X(8) X(9) X(10) X(11) \
  X(12) X(13) X(14) X(15) X(16) X(17) X(18) X(19) X(20) X(21) X(22) X(23) \
  X(24) X(25) X(26) X(27) X(28) X(29) X(30) X(31)

__global__ void __launch_bounds__(256, 4)
k_final(const float* __restrict__ P, const float* __restrict__ Eq,
        const float* __restrict__ Ec, const float* __restrict__ qadj,
        const float* __restrict__ cadj, float* __restrict__ out) {
    __shared__ float Ps[400];
    __shared__ unsigned char spsh[192], dpsh[192];
    int xcd = blockIdx.x & 7, slot = blockIdx.x >> 3;  // grid 288
    int b = xcd + 8 * (slot / 6), qt = slot % 6;
    int t = threadIdx.x, w = t >> 6, lane = t & 63;

    // ---- issue per-lane tile loads FIRST: they fly under staging + barrier ----
    int l31 = lane & 31;
    int q = qt * 32 + l31;
    bool qv = q < kNP;
    int sqe = 0, dqe = 0;
    { int qc = qv ? q : 0; pair_sd(qc, sqe, dqe); }    // compute, don't wait on LDS
    float acv = qv ? cadj[b * 400 + sqe * 20 + dqe] : 0.f;
    const float* ecb = Ec + (b * kNP + qt * 32) * 64 + lane;
#define EC_DECL(i) float ec##i = (qt * 32 + i < kNP) ? ecb[i * 64] : 0.f;
    EC_ALL(EC_DECL)
#undef EC_DECL

    if (t < 192) {
        int s = 0, d = 0;
        if (t < kNP) pair_sd(t, s, d);
        spsh[t] = (unsigned char)s;
        dpsh[t] = (unsigned char)d;
    }
    for (int i = t; i < 400; i += 256) Ps[i] = P[b * 400 + i];
    __syncthreads();

    int sq = sqe, dq = dqe;

    float a0 = 0.f, a1 = 0.f, a2 = 0.f, a3 = 0.f;
    int pp = w;
    float aqc = qadj[b * 400 + spsh[pp] * 20 + dpsh[pp]];
    float eqc = Eq[(b * kNP + pp) * 64 + lane];
    while (pp < kNP) {
        int pn = pp + 4;
        float aqn = 0.f, eqn = 0.f;
        if (pn < kNP) {
            aqn = qadj[b * 400 + spsh[pn] * 20 + dpsh[pn]];
            eqn = Eq[(b * kNP + pn) * 64 + lane];
        }
        int sp = spsh[pp], dp = dpsh[pp];
        float eT = Ps[sp * 20 + sq] * Ps[dp * 20 + dq]
                 + Ps[sp * 20 + dq] * Ps[dp * 20 + sq];
        float wqv = qv ? ((aqc > 0.5f) ? (1.f - acv) : acv) * eT : 0.f;
#define EC_FMA(i) { float d_ = fabsf(eqc - ec##i); \
        if ((i & 3) == 0) a0 = fmaf(bc(wqv, i), d_, a0); \
        else if ((i & 3) == 1) a1 = fmaf(bc(wqv, i), d_, a1); \
        else if ((i & 3) == 2) a2 = fmaf(bc(wqv, i), d_, a2); \
        else a3 = fmaf(bc(wqv, i), d_, a3); }
        EC_ALL(EC_FMA)
#undef EC_FMA
        aqc = aqn; eqc = eqn; pp = pn;
    }
    float partial = (a0 + a1) + (a2 + a3);
    #pragma unroll
    for (int off = 32; off; off >>= 1) partial += __shfl_down(partial, off, 64);
    if (lane == 0) atomicAdd(&out[b], partial);
}

extern "C" void kernel_launch(void* const* d_in, const int* in_sizes, int n_in,
                              void* d_out, int out_size, void* d_ws, size_t ws_size,
                              hipStream_t stream) {
    auto f = [&](int i) { return (const float*)d_in[i]; };
    const float* nf   = f(0);
    const float* ef   = f(1);
    const float* qadj = f(2);
    const float* cadj = f(3);
    const int* from_idx = (const int*)d_in[24];
    const int* to_idx   = (const int*)d_in[25];
    float* out = (float*)d_out;

    float* ws  = (float*)d_ws;
    float* h   = ws;                       // 55296
    float* ee  = h   + 55296;              // 107520
    float* agg = ee  + 107520;             // 110592
    float* Hq  = agg + 110592;             // 30720
    float* Hc  = Hq  + 30720;              // 30720
    float* tq  = Hc  + 30720;              // 19200
    float* tc  = tq  + 19200;              // 19200
    float* P   = tc  + 19200;              // 19200
    float* Eq  = P   + 19200;              // 583680
    float* Ec  = Eq  + 583680;             // 583680

    k_enc<<<432, 256, 0, stream>>>(nf, f(4), f(5), ef, f(6), f(7), h, ee, agg, out);
    for (int it = 0; it < 5; ++it) {
        k_msg<<<840, 256, 0, stream>>>(h, ee, from_idx, to_idx,
                                       f(8), f(9), f(10), f(11), agg);
        k_upd<<<216, 256, 0, stream>>>(h, agg, f(12), f(13), f(14), f(15));
    }
    k_sink_t<<<480, 256, 0, stream>>>(h, f(16), f(17), f(18), f(19), Hq, Hc, tq, tc);
    k_sinkhorn<<<48, 64, 0, stream>>>(tq, tc, Hq, P, out);
    k_edge_emb<<<1152, 256, 0, stream>>>(Hq, Hc, qadj, cadj,
                                         f(20), f(21), f(22), f(23), Eq, Ec);
    k_final<<<288, 256, 0, stream>>>(P, Eq, Ec, qadj, cadj, out);
}

// Round 19
// 150.973 us; speedup vs baseline: 1.0576x; 1.0001x over previous
//
#include <hip/hip_runtime.h>

// GRAPHEDX forward — fp32 v19: v18 (151.0us best) with ONE structural change:
// Hq/Hc are pure copies of h -> edge_emb + sinkhorn read h directly, so
// sink_t and edge_emb are independent and share one dispatch (k_mid,
// block-range partitioned: 480 sink blocks || 1152 emb blocks). 14 dispatches.

constexpr int kB    = 48;
constexpr int kNM   = 20;
constexpr int kD    = 32;
constexpr int kNP   = 190;
constexpr int kNTOT = 1728;
constexpr int kIters = 20;
constexpr float kInvT = 100.0f;

__device__ __forceinline__ void pair_sd(int p, int& s, int& d) {
    int row = 0, rem = p;
    #pragma unroll
    for (int r = 0; r < 19; ++r) {
        int len = 19 - r;
        if (rem < len) { row = r; break; }
        rem -= len;
    }
    s = row; d = row + 1 + rem;
}

__device__ __forceinline__ float bc(float v, int k) {
    return __int_as_float(__builtin_amdgcn_readlane(__float_as_int(v), k));
}

__device__ __forceinline__ void lse20(float (&r)[20]) {
    float m01 = fmaxf(r[0], r[1]),  m23 = fmaxf(r[2], r[3]),
          m45 = fmaxf(r[4], r[5]),  m67 = fmaxf(r[6], r[7]),
          m89 = fmaxf(r[8], r[9]),  mab = fmaxf(r[10], r[11]),
          mcd = fmaxf(r[12], r[13]), mef = fmaxf(r[14], r[15]),
          mgh = fmaxf(r[16], r[17]), mij = fmaxf(r[18], r[19]);
    float n0 = fmaxf(m01, m23), n1 = fmaxf(m45, m67), n2 = fmaxf(m89, mab),
          n3 = fmaxf(mcd, mef), n4 = fmaxf(mgh, mij);
    float m = fmaxf(fmaxf(fmaxf(n0, n1), fmaxf(n2, n3)), n4);
    float e[20];
    #pragma unroll
    for (int k = 0; k < 20; ++k) e[k] = __expf(r[k] - m);
    float s01 = e[0] + e[1],  s23 = e[2] + e[3],  s45 = e[4] + e[5],
          s67 = e[6] + e[7],  s89 = e[8] + e[9],  sab = e[10] + e[11],
          scd = e[12] + e[13], sef = e[14] + e[15], sgh = e[16] + e[17],
          sij = e[18] + e[19];
    float t0 = s01 + s23, t1 = s45 + s67, t2 = s89 + sab,
          t3 = scd + sef, t4 = sgh + sij;
    float s = ((t0 + t1) + (t2 + t3)) + t4;
    float l = m + __logf(s);
    #pragma unroll
    for (int k = 0; k < 20; ++k) r[k] -= l;
}

// ---------------- fused encoders + zeroing ----------------
__global__ void k_enc(const float* __restrict__ nf, const float* __restrict__ nw,
                      const float* __restrict__ nb, const float* __restrict__ ef,
                      const float* __restrict__ ew, const float* __restrict__ eb,
                      float* __restrict__ h, float* __restrict__ ee,
                      float* __restrict__ agg, float* __restrict__ out) {
    int tid = blockIdx.x * 256 + threadIdx.x;
    int stride = gridDim.x * 256;
    for (int i = tid; i < kNTOT * 32; i += stride) {
        int n = i >> 5, c = i & 31;
        float acc = nb[c];
        const float* row = nf + n * 16;
        #pragma unroll
        for (int k = 0; k < 16; ++k) acc = fmaf(row[k], nw[k * 32 + c], acc);
        h[i] = acc;
    }
    for (int i = tid; i < 6720 * 16; i += stride) {
        int n = i >> 4, c = i & 15;
        float acc = eb[c];
        const float* row = ef + n * 8;
        #pragma unroll
        for (int k = 0; k < 8; ++k) acc = fmaf(row[k], ew[k * 16 + c], acc);
        ee[i] = acc;
    }
    for (int i = tid; i < kNTOT * 64; i += stride) agg[i] = 0.f;
    if (tid < kB) out[tid] = 0.f;
}

// ---------------- message + scatter: readlane MLP, 2 edges/wave ----------------
__global__ void __launch_bounds__(256)
k_msg(const float* __restrict__ h, const float* __restrict__ ee,
      const int* __restrict__ fidx, const int* __restrict__ tidx,
      const float* __restrict__ w1, const float* __restrict__ b1,
      const float* __restrict__ w2, const float* __restrict__ b2,
      float* __restrict__ agg) {
    int w = threadIdx.x >> 6, lane = threadIdx.x & 63;
    int e0 = (blockIdx.x * 4 + w) * 2;                 // 840 blocks, 6720 edges
    int toj[2]; float xa[2], xb[2], acc[2], o[2];
    #pragma unroll
    for (int j = 0; j < 2; ++j) {
        int e = e0 + j;
        int fr = fidx[e]; toj[j] = tidx[e];
        xa[j] = h[(lane < 32 ? fr : toj[j]) * kD + (lane & 31)];
        xb[j] = ee[e * 16 + (lane & 15)];
        acc[j] = b1[lane];
    }
    #pragma unroll
    for (int k = 0; k < 64; ++k) {
        float w1k = w1[k * 64 + lane];
        #pragma unroll
        for (int j = 0; j < 2; ++j) acc[j] = fmaf(bc(xa[j], k), w1k, acc[j]);
    }
    #pragma unroll
    for (int k = 0; k < 16; ++k) {
        float w1k = w1[(64 + k) * 64 + lane];
        #pragma unroll
        for (int j = 0; j < 2; ++j) acc[j] = fmaf(bc(xb[j], k), w1k, acc[j]);
    }
    #pragma unroll
    for (int j = 0; j < 2; ++j) { acc[j] = fmaxf(acc[j], 0.f); o[j] = b2[lane]; }
    #pragma unroll
    for (int k = 0; k < 64; ++k) {
        float w2k = w2[k * 64 + lane];
        #pragma unroll
        for (int j = 0; j < 2; ++j) o[j] = fmaf(bc(acc[j], k), w2k, o[j]);
    }
    #pragma unroll
    for (int j = 0; j < 2; ++j) atomicAdd(&agg[toj[j] * 64 + lane], o[j]);
}

// ---------------- node update: readlane MLP, 2 nodes/wave ----------------
__global__ void __launch_bounds__(256)
k_upd(float* __restrict__ h, float* __restrict__ agg,
      const float* __restrict__ w1, const float* __restrict__ b1,
      const float* __restrict__ w2, const float* __restrict__ b2) {
    int w = threadIdx.x >> 6, lane = threadIdx.x & 63;
    int n0 = (blockIdx.x * 4 + w) * 2;                 // 216 blocks, 1728 nodes
    float xa[2], xb[2], acc[2], o[2];
    #pragma unroll
    for (int j = 0; j < 2; ++j) {
        int n = n0 + j;
        xa[j] = agg[n * 64 + lane];
        agg[n * 64 + lane] = 0.f;                      // re-zero for next round
        xb[j] = h[n * kD + (lane & 31)];
        acc[j] = b1[lane];
    }
    #pragma unroll
    for (int k = 0; k < 64; ++k) {
        float w1k = w1[k * 64 + lane];
        #pragma unroll
        for (int j = 0; j < 2; ++j) acc[j] = fmaf(bc(xa[j], k), w1k, acc[j]);
    }
    #pragma unroll
    for (int k = 0; k < 32; ++k) {
        float w1k = w1[(64 + k) * 64 + lane];
        #pragma unroll
        for (int j = 0; j < 2; ++j) acc[j] = fmaf(bc(xb[j], k), w1k, acc[j]);
    }
    #pragma unroll
    for (int j = 0; j < 2; ++j) { acc[j] = fmaxf(acc[j], 0.f); o[j] = b2[lane & 31]; }
    #pragma unroll
    for (int k = 0; k < 64; ++k) {
        float w2k = w2[k * 32 + (lane & 31)];
        #pragma unroll
        for (int j = 0; j < 2; ++j) o[j] = fmaf(bc(acc[j], k), w2k, o[j]);
    }
    if (lane < 32) {
        #pragma unroll
        for (int j = 0; j < 2; ++j) h[(n0 + j) * kD + lane] += o[j];
    }
}

// ---------------- k_mid: sink_t (blocks 0..479) || edge_emb (blocks 480..1631) ----
__global__ void __launch_bounds__(256)
k_mid(const float* __restrict__ h,
      const float* __restrict__ qadj, const float* __restrict__ cadj,
      const float* __restrict__ sw1, const float* __restrict__ sb1,
      const float* __restrict__ sw2, const float* __restrict__ sb2,
      const float* __restrict__ lw1, const float* __restrict__ lb1,
      const float* __restrict__ lw2, const float* __restrict__ lb2,
      float* __restrict__ tq, float* __restrict__ tc,
      float* __restrict__ Eq, float* __restrict__ Ec) {
    __shared__ float xs[4][32];
    __shared__ float hs[4][20];
    int w = threadIdx.x >> 6, lane = threadIdx.x & 63;

    if (blockIdx.x < 480) {
        // ---- sink_t branch (tq/tc only; reads h directly; no Hq/Hc) ----
        int xcd = blockIdx.x & 7, slot = blockIdx.x >> 3;
        int b = xcd + 8 * (slot / 10);
        int task = (slot % 10) * 4 + w;
        int side = task >= 20;
        int i = task - side * 20;
        if (lane < 32) {
            float v;
            if (side == 0) v = h[(b * 36 + i) * kD + lane];
            else           v = (i < 16) ? h[(b * 36 + 20 + i) * kD + lane] : 0.f;
            xs[w][lane] = v;
        }
        __syncthreads();
        if (lane < kNM) {
            float acc = sb1[lane];
            #pragma unroll
            for (int k = 0; k < kD; ++k) acc += xs[w][k] * sw1[k * kNM + lane];
            hs[w][lane] = fmaxf(acc, 0.f);
        }
        __syncthreads();
        if (lane < kNM) {
            float o = sb2[lane];
            #pragma unroll
            for (int k = 0; k < kNM; ++k) o += hs[w][k] * sw2[k * kNM + lane];
            (side ? tc : tq)[(b * kNM + i) * kNM + lane] = o;
        }
        return;
    }

    // ---- edge_emb branch (reads h directly with pad-zero) ----
    int bid = blockIdx.x - 480;                        // 0..1151
    int xcd = bid & 7, slot = bid >> 3;
    int b = xcd + 8 * (slot / 24);
    int r = slot % 24;
    float xa[4], ev[4], af[4], ab[4];
    int sidej[4], pj[4];
    #pragma unroll
    for (int j = 0; j < 4; ++j) {
        int tloc = r * 16 + w * 4 + j;
        if (tloc >= 380) tloc = 379;
        sidej[j] = tloc / kNP; pj[j] = tloc % kNP;
        int s, d; pair_sd(pj[j], s, d);
        int rr = (lane < 32) ? s : d;
        int cc = lane & 31;
        float v;
        if (!sidej[j]) v = h[(b * 36 + rr) * kD + cc];
        else           v = (rr < 16) ? h[(b * 36 + 20 + rr) * kD + cc] : 0.f;
        xa[j] = v;
        ev[j] = (sidej[j] ? cadj : qadj)[b * 400 + s * 20 + d];
        float bb = lb1[lane];
        af[j] = bb; ab[j] = bb;
    }
    #pragma unroll
    for (int k = 0; k < 64; ++k) {
        float w1k = lw1[k * 64 + lane];
        #pragma unroll
        for (int j = 0; j < 4; ++j) {
            af[j] = fmaf(bc(xa[j], k),      w1k, af[j]);
            ab[j] = fmaf(bc(xa[j], k ^ 32), w1k, ab[j]);
        }
    }
    {
        float w1e = lw1[64 * 64 + lane];
        #pragma unroll
        for (int j = 0; j < 4; ++j) {
            af[j] = fmaf(ev[j], w1e, af[j]);
            ab[j] = fmaf(ev[j], w1e, ab[j]);
        }
    }
    float hid[4], o[4];
    #pragma unroll
    for (int j = 0; j < 4; ++j) {
        hid[j] = fmaxf(af[j], 0.f) + fmaxf(ab[j], 0.f);
        o[j] = 2.f * lb2[lane];
    }
    #pragma unroll
    for (int k = 0; k < 64; ++k) {
        float w2k = lw2[k * 64 + lane];
        #pragma unroll
        for (int j = 0; j < 4; ++j) o[j] = fmaf(bc(hid[j], k), w2k, o[j]);
    }
    #pragma unroll
    for (int j = 0; j < 4; ++j)
        (sidej[j] ? Ec : Eq)[(b * kNP + pj[j]) * 64 + lane] = o[j];
}

// ---------------- Sinkhorn (v6; node_align reads h directly) ----------------
__global__ void k_sinkhorn(const float* __restrict__ tq, const float* __restrict__ tc,
                           const float* __restrict__ h,
                           float* __restrict__ P, float* __restrict__ out) {
    __shared__ float tcS[400];
    __shared__ float tr[20 * 21];
    int b = blockIdx.x, lane = threadIdx.x;
    for (int i = lane; i < 400; i += 64) tcS[i] = tc[b * 400 + i];
    int i20 = lane < 20 ? lane : 0;
    float tqr[20];
    #pragma unroll
    for (int k = 0; k < 20; ++k) tqr[k] = tq[(b * 20 + i20) * 20 + k];
    __syncthreads();
    float r[20];
    #pragma unroll
    for (int j = 0; j < 20; ++j) {
        float c = 0.f;
        #pragma unroll
        for (int k = 0; k < 20; ++k) c += fabsf(tqr[k] - tcS[j * 20 + k]);
        r[j] = -c * kInvT;
    }
    for (int it = 0; it < kIters; ++it) {
        lse20(r);
        if (lane < 20) {
            #pragma unroll
            for (int j = 0; j < 20; ++j) tr[lane * 21 + j] = r[j];
        }
        __syncthreads();
        if (lane < 20) {
            #pragma unroll
            for (int i = 0; i < 20; ++i) r[i] = tr[i * 21 + lane];
        }
        __syncthreads();
        lse20(r);
        if (lane < 20) {
            #pragma unroll
            for (int i = 0; i < 20; ++i) tr[i * 21 + lane] = r[i];
        }
        __syncthreads();
        if (lane < 20) {
            #pragma unroll
            for (int j = 0; j < 20; ++j) r[j] = tr[lane * 21 + j];
        }
        __syncthreads();
    }
    float part = 0.f;
    if (lane < 20) {
        float pv[20];
        #pragma unroll
        for (int j = 0; j < 20; ++j) pv[j] = __expf(r[j]);
        float* Pb = P + b * 400 + lane * 20;
        #pragma unroll
        for (int j = 0; j < 20; ++j) Pb[j] = pv[j];
        float pr4 = (pv[16] + pv[17]) + (pv[18] + pv[19]);
        float l1 = 0.f;
        const float* hq = h + (b * 36 + lane) * kD;    // Hq row i = h row i (<20)
        #pragma unroll
        for (int k = 0; k < 32; ++k) l1 += fabsf(hq[k]);
        part = pr4 * l1;
    }
    #pragma unroll
    for (int off = 32; off; off >>= 1) part += __shfl_down(part, off, 64);
    if (lane == 0) atomicAdd(&out[b], part);
}

// ---------------- edge_align: v18 (ec/acv issued before staging) ----------
#define EC_ALL(X) X(0) X(1) X(2) X(3) X(4) X(5) X(6) X(7) X(8) X(9) X(10) X(11) \
  X(12) X(13) X(14) X(15) X(16) X(17) X(18) X(19) X(20) X(21) X(22) X(23) \
  X(24) X(25) X(26) X(27) X(28) X(29) X(30) X(31)

__global__ void __launch_bounds__(256, 4)
k_final(const float* __restrict__ P, const float* __restrict__ Eq,
        const float* __restrict__ Ec, const float* __restrict__ qadj,
        const float* __restrict__ cadj, float* __restrict__ out) {
    __shared__ float Ps[400];
    __shared__ unsigned char spsh[192], dpsh[192];
    int xcd = blockIdx.x & 7, slot = blockIdx.x >> 3;  // grid 288
    int b = xcd + 8 * (slot / 6), qt = slot % 6;
    int t = threadIdx.x, w = t >> 6, lane = t & 63;

    int l31 = lane & 31;
    int q = qt * 32 + l31;
    bool qv = q < kNP;
    int sqe = 0, dqe = 0;
    { int qc = qv ? q : 0; pair_sd(qc, sqe, dqe); }
    float acv = qv ? cadj[b * 400 + sqe * 20 + dqe] : 0.f;
    const float* ecb = Ec + (b * kNP + qt * 32) * 64 + lane;
#define EC_DECL(i) float ec##i = (qt * 32 + i < kNP) ? ecb[i * 64] : 0.f;
    EC_ALL(EC_DECL)
#undef EC_DECL

    if (t < 192) {
        int s = 0, d = 0;
        if (t < kNP) pair_sd(t, s, d);
        spsh[t] = (unsigned char)s;
        dpsh[t] = (unsigned char)d;
    }
    for (int i = t; i < 400; i += 256) Ps[i] = P[b * 400 + i];
    __syncthreads();

    int sq = sqe, dq = dqe;

    float a0 = 0.f, a1 = 0.f, a2 = 0.f, a3 = 0.f;
    int pp = w;
    float aqc = qadj[b * 400 + spsh[pp] * 20 + dpsh[pp]];
    float eqc = Eq[(b * kNP + pp) * 64 + lane];
    while (pp < kNP) {
        int pn = pp + 4;
        float aqn = 0.f, eqn = 0.f;
        if (pn < kNP) {
            aqn = qadj[b * 400 + spsh[pn] * 20 + dpsh[pn]];
            eqn = Eq[(b * kNP + pn) * 64 + lane];
        }
        int sp = spsh[pp], dp = dpsh[pp];
        float eT = Ps[sp * 20 + sq] * Ps[dp * 20 + dq]
                 + Ps[sp * 20 + dq] * Ps[dp * 20 + sq];
        float wqv = qv ? ((aqc > 0.5f) ? (1.f - acv) : acv) * eT : 0.f;
#define EC_FMA(i) { float d_ = fabsf(eqc - ec##i); \
        if ((i & 3) == 0) a0 = fmaf(bc(wqv, i), d_, a0); \
        else if ((i & 3) == 1) a1 = fmaf(bc(wqv, i), d_, a1); \
        else if ((i & 3) == 2) a2 = fmaf(bc(wqv, i), d_, a2); \
        else a3 = fmaf(bc(wqv, i), d_, a3); }
        EC_ALL(EC_FMA)
#undef EC_FMA
        aqc = aqn; eqc = eqn; pp = pn;
    }
    float partial = (a0 + a1) + (a2 + a3);
    #pragma unroll
    for (int off = 32; off; off >>= 1) partial += __shfl_down(partial, off, 64);
    if (lane == 0) atomicAdd(&out[b], partial);
}

extern "C" void kernel_launch(void* const* d_in, const int* in_sizes, int n_in,
                              void* d_out, int out_size, void* d_ws, size_t ws_size,
                              hipStream_t stream) {
    auto f = [&](int i) { return (const float*)d_in[i]; };
    const float* nf   = f(0);
    const float* ef   = f(1);
    const float* qadj = f(2);
    const float* cadj = f(3);
    const int* from_idx = (const int*)d_in[24];
    const int* to_idx   = (const int*)d_in[25];
    float* out = (float*)d_out;

    float* ws  = (float*)d_ws;
    float* h   = ws;                       // 55296
    float* ee  = h   + 55296;              // 107520
    float* agg = ee  + 107520;             // 110592
    float* tq  = agg + 110592;             // 19200
    float* tc  = tq  + 19200;              // 19200
    float* P   = tc  + 19200;              // 19200
    float* Eq  = P   + 19200;              // 583680
    float* Ec  = Eq  + 583680;             // 583680

    k_enc<<<432, 256, 0, stream>>>(nf, f(4), f(5), ef, f(6), f(7), h, ee, agg, out);
    for (int it = 0; it < 5; ++it) {
        k_msg<<<840, 256, 0, stream>>>(h, ee, from_idx, to_idx,
                                       f(8), f(9), f(10), f(11), agg);
        k_upd<<<216, 256, 0, stream>>>(h, agg, f(12), f(13), f(14), f(15));
    }
    k_mid<<<1632, 256, 0, stream>>>(h, qadj, cadj,
                                    f(16), f(17), f(18), f(19),
                                    f(20), f(21), f(22), f(23),
                                    tq, tc, Eq, Ec);
    k_sinkhorn<<<48, 64, 0, stream>>>(tq, tc, h, P, out);
    k_final<<<288, 256, 0, stream>>>(P, Eq, Ec, qadj, cadj, out);
}